// Round 12
// baseline (27.495 us; speedup 1.0000x reference)
//
#include <hip/hip_runtime.h>
#include <hip/hip_bf16.h>

typedef short short8 __attribute__((ext_vector_type(8)));
typedef float f32x4 __attribute__((ext_vector_type(4)));

union FragAB { unsigned long long l[2]; int i[4]; short8 v; };

// Round-12: small-block variant — 32p x 256j per block, 2048 blocks.
//
// Swapped-operand formulation: D[p=(b,f), j] = sum_i A[p,i] * B[i,j]
//   A[p,i] = bf16(x[b, sx, i, f])            (Xts rows, k-contiguous)
//   B[i,j] = T[j,i] = wfor[255 + diag - j + i]
//   wfor[q] = krow[q] for q in [0,255], 0 elsewhere (zero-pad = triangular
//   mask AND the diagonal roll-by-one, which switches divisor to j+1-diag).
// Four shifted copies of wfor (copy s holds wfor shifted +s, read via
// byte = s*674 + 2*w) make every lane's window 8-byte aligned.
//
// Block = (hy, sx, np): rows p = (2np+bl)*16 + f (bl=0..1), all 256 j.
// Wave (wp=bl, par): 16 p-rows x 128 j as 8 parity-interleaved 16-col
// groups (j0 = 32g+16par). Group g active at steps st<=g, completes at
// st==g -> 1 store per completion, uniform 8-step waves, 1 A-b128/step.
// LDS 20.1 KB -> 6 blocks/CU (lb(256,6)): halved front-end per block,
// 6 staggered front-ends per CU, smoother generation pipelining.
__global__ __launch_bounds__(256, 6)
void k_fused(const float* __restrict__ x,     // [16,8,256,16]
             const float* __restrict__ kern,  // [4,8,8,256]
             float* __restrict__ out)         // [16,4,8,8,256,16]
{
    __shared__ __align__(16) ushort Xts[32 * 264];   // [p][k], row 528 B
    __shared__ __align__(8)  ushort wforL[4][336];   // [shift][q]
    __shared__ float rtab[256];

    const int blk = blockIdx.x;             // 0..2047
    const int hy = blk & 31;                // h*8 + sy
    const int sx = (blk >> 5) & 7;
    const int np = blk >> 8;                // b-pair index 0..7
    const int h = hy >> 3, sy = hy & 7;
    const int diag = (sx == sy) ? 1 : 0;
    const int t = threadIdx.x;

    // ---- wfor shift-copies (bf16) ----
    {
        const float* krow = kern + ((h * 8 + sx) * 8 + sy) * 256;
        #pragma unroll
        for (int s = 0; s < 4; ++s) {
            #pragma unroll
            for (int pass = 0; pass < 2; ++pass) {
                int q = t + pass * 256;
                if (q < 336) {
                    int src = q - s;
                    float v = (src >= 0 && src < 256) ? krow[src] : 0.0f;
                    __hip_bfloat16 hv = __float2bfloat16(v);
                    wforL[s][q] = reinterpret_cast<ushort&>(hv);
                }
            }
        }
    }
    // ---- reciprocal table for this block's diag ----
    {
        int denom = t + 1 - diag;
        rtab[t] = (denom > 0) ? (1.0f / (float)denom) : 0.0f;
    }
    // ---- stage + transpose 2-b x-slice -> Xts: Xts[bl*16+f][k] ----
    {
        const float4* xbase = reinterpret_cast<const float4*>(x);
        #pragma unroll
        for (int it = 0; it < 4; ++it) {
            int id = it * 256 + t;              // 0..1023
            int fq = id & 3;
            int k2 = (id >> 2) & 127;
            int bl = id >> 9;                   // local b 0..1
            const float4* rowp = xbase + ((size_t)((np * 2 + bl) * 8 + sx)) * 1024;
            float4 a = rowp[(2 * k2) * 4 + fq];
            float4 cq = rowp[(2 * k2 + 1) * 4 + fq];
            #pragma unroll
            for (int e = 0; e < 4; ++e) {
                float va = (&a.x)[e], vb = (&cq.x)[e];
                __hip_bfloat16 ha = __float2bfloat16(va);
                __hip_bfloat16 hb = __float2bfloat16(vb);
                uint u = (uint)reinterpret_cast<ushort&>(ha) |
                         ((uint)reinterpret_cast<ushort&>(hb) << 16);
                int row = bl * 16 + fq * 4 + e;
                *reinterpret_cast<uint*>(reinterpret_cast<char*>(Xts) + row * 528 + k2 * 4) = u;
            }
        }
    }
    __syncthreads();

    const int lane = t & 63, wid = t >> 6;
    const int laneM = lane & 15, laneG = lane >> 4;
    const int wp  = wid >> 1;                   // which b of the pair
    const int par = wid & 1;                    // j-group parity

    const char* XtsB = reinterpret_cast<const char*>(Xts);
    const char* WB = reinterpret_cast<const char*>(wforL);
    const int abyte = (16 * wp + laneM) * 528 + laneG * 16;
    const int b_ = np * 2 + wp;
    float* const oblk = out + (((size_t)(b_ * 4 + h) * 8 + sx) * 8 + sy) * 4096
                        + laneG * 4;

    // B window for group g at step kc: elems w00 - 32g + kc + e,
    // w00 = 255 + diag - 16par - laneM + 8laneG.
    const int w00 = 255 + diag - 16 * par - laneM + 8 * laneG;
    const int s = (laneM - diag + 1) & 3;       // (w00+s) % 4 == 0
    const int bBw = s * 674 + 2 * w00;          // byte base (incl. +s shift)

    f32x4 acc[8];
    #pragma unroll
    for (int g = 0; g < 8; ++g)
        acc[g] = (f32x4){0.0f, 0.0f, 0.0f, 0.0f};

    #pragma unroll
    for (int st = 0; st < 8; ++st) {
        const int kc = 32 * st;
        FragAB af;
        {
            const int4 raw = *reinterpret_cast<const int4*>(XtsB + abyte + kc * 2);
            af.i[0] = raw.x; af.i[1] = raw.y;
            af.i[2] = raw.z; af.i[3] = raw.w;
        }
        #pragma unroll
        for (int g = 0; g < 8; ++g) {
            if (g >= st) {                      // group active this step
                FragAB bf;
                const char* p = WB + bBw - 64 * g + kc * 2;
                bf.l[0] = *reinterpret_cast<const unsigned long long*>(p);
                bf.l[1] = *reinterpret_cast<const unsigned long long*>(p + 8);
                acc[g] = __builtin_amdgcn_mfma_f32_16x16x32_bf16(
                    af.v, bf.v, acc[g], 0, 0, 0);
            }
            if (g == st) {                      // group complete -> store now
                const int j = 32 * g + 16 * par + laneM;
                f32x4 v = acc[g] * rtab[j];
                __builtin_nontemporal_store(
                    v, reinterpret_cast<f32x4*>(oblk + (size_t)j * 16));
            }
        }
    }
}

extern "C" void kernel_launch(void* const* d_in, const int* in_sizes, int n_in,
                              void* d_out, int out_size, void* d_ws, size_t ws_size,
                              hipStream_t stream) {
    const float* x    = (const float*)d_in[0];   // [16,8,256,16]
    const float* kern = (const float*)d_in[1];   // [4,8,8,256]
    float* out = (float*)d_out;                  // [16,4,8,8,256,16]

    k_fused<<<2048, 256, 0, stream>>>(x, kern, out);
}

// Round 13
// 19.695 us; speedup vs baseline: 1.3960x; 1.3960x over previous
//
#include <hip/hip_runtime.h>
#include <hip/hip_bf16.h>

typedef short short8 __attribute__((ext_vector_type(8)));
typedef float f32x4 __attribute__((ext_vector_type(4)));

union FragAB { unsigned long long l[2]; int i[4]; short8 v; };

// Round-13 = round-9 structure (best known, 20.55 us) with ONE change:
// minimal wfor build (1 global load + 1 cvt + 4 shifted LDS stores per
// thread, vs 8 loads + 8 cvts) — shortens every block's serial front-end.
//
// Swapped-operand formulation: D[p=(b,f), j] = sum_i A[p,i] * B[i,j]
//   A[p,i] = bf16(x[b, sx, i, f])            (Xts rows, k-contiguous)
//   B[i,j] = T[j,i] = wfor[255 + diag - j + i]
//   wfor[q] = krow[q] for q in [0,255], 0 elsewhere (zero-pad = triangular
//   mask AND the diagonal roll-by-one, which switches divisor to j+1-diag).
// Copy s holds wfor shifted +s (wforL[s][q] = wfor[q-s]); reads use
// byte = s*674 + 2*w (674 = 672 row stride + 2 for the +s element shift),
// making every lane's 8-element window 8-byte aligned -> 2x ds_read_b64.
//
// Block = (hy, sx, nt) computes a 64p x 256j tile; the 4 waves take the 4
// j-bands (kmax = 64*(wid+1)) -> identical total K-work per block; light
// waves' stores drain while heavy waves compute. LDS 37.5 KB, lb(256,3).
// Nontemporal stores (neutral-to-slightly-positive in the R9 A/B).
__global__ __launch_bounds__(256, 3)
void k_fused(const float* __restrict__ x,     // [16,8,256,16]
             const float* __restrict__ kern,  // [4,8,8,256]
             float* __restrict__ out)         // [16,4,8,8,256,16]
{
    __shared__ __align__(16) ushort Xts[64 * 264];   // [p][k], row 528 B
    __shared__ __align__(8)  ushort wforL[4][336];   // [shift][q]
    __shared__ float rtab[256];

    const int blk = blockIdx.x;             // 0..1023
    const int hy = blk & 31;                // h*8 + sy
    const int sx = (blk >> 5) & 7;
    const int nt = blk >> 8;                // p-quarter (b-quad)
    const int h = hy >> 3, sy = hy & 7;
    const int diag = (sx == sy) ? 1 : 0;
    const int t = threadIdx.x;

    // ---- minimal wfor build: 1 load, 1 cvt, 4 shifted stores, zero tails --
    {
        const float* krow = kern + ((h * 8 + sx) * 8 + sy) * 256;
        float v = krow[t];
        __hip_bfloat16 hv = __float2bfloat16(v);
        ushort u = reinterpret_cast<ushort&>(hv);
        #pragma unroll
        for (int s = 0; s < 4; ++s)
            wforL[s][t + s] = u;                 // wforL[s][q] = wfor[q-s]
        if (t < 88) {                            // zero tail q in [256+s, 336)
            #pragma unroll
            for (int s = 0; s < 4; ++s) {
                int q = 256 + s + t;
                if (q < 336) wforL[s][q] = 0;
            }
        }
        if (t < 4) {                             // zero head q in [0, s)
            #pragma unroll
            for (int s = 1; s < 4; ++s)
                if (t < s) wforL[s][t] = 0;
        }
    }
    // ---- reciprocal table for this block's diag ----
    {
        int denom = t + 1 - diag;
        rtab[t] = (denom > 0) ? (1.0f / (float)denom) : 0.0f;
    }
    // ---- stage + transpose x quarter-slice -> Xts: Xts[bl*16+f][k] ----
    {
        const float4* xbase = reinterpret_cast<const float4*>(x);
        #pragma unroll
        for (int it = 0; it < 8; ++it) {
            int id = it * 256 + t;              // 0..2047
            int fq = id & 3;
            int k2 = (id >> 2) & 127;
            int bl = id >> 9;                   // local b 0..3
            const float4* rowp = xbase + ((size_t)((nt * 4 + bl) * 8 + sx)) * 1024;
            float4 a = rowp[(2 * k2) * 4 + fq];
            float4 cq = rowp[(2 * k2 + 1) * 4 + fq];
            #pragma unroll
            for (int e = 0; e < 4; ++e) {
                float va = (&a.x)[e], vb = (&cq.x)[e];
                __hip_bfloat16 ha = __float2bfloat16(va);
                __hip_bfloat16 hb = __float2bfloat16(vb);
                uint u = (uint)reinterpret_cast<ushort&>(ha) |
                         ((uint)reinterpret_cast<ushort&>(hb) << 16);
                int row = bl * 16 + fq * 4 + e;
                *reinterpret_cast<uint*>(reinterpret_cast<char*>(Xts) + row * 528 + k2 * 4) = u;
            }
        }
    }
    __syncthreads();

    const int lane = t & 63, wid = t >> 6;
    const int laneM = lane & 15, laneG = lane >> 4;
    const int wj0 = wid * 64;                   // wave's j base
    const int kmax = wj0 + 64;                  // triangle skip

    const char* XtsB = reinterpret_cast<const char*>(Xts);
    const char* WB = reinterpret_cast<const char*>(wforL);
    const int abyte = laneM * 528 + laneG * 16;

    // B element e (lane) for frag n, step kc: wfor[w00 + kc - 16n + e]
    const int w00 = 255 + diag - wj0 - laneM + 8 * laneG;
    const int s = (laneM - diag + 1) & 3;       // makes (w00+s) % 4 == 0
    const int bB = s * 674 + 2 * w00;           // byte base (incl. +s shift)

    f32x4 acc[4][4];
    #pragma unroll
    for (int m = 0; m < 4; ++m)
        #pragma unroll
        for (int n = 0; n < 4; ++n)
            acc[m][n] = (f32x4){0.0f, 0.0f, 0.0f, 0.0f};

    for (int kc = 0; kc < kmax; kc += 32) {
        FragAB af[4];
        #pragma unroll
        for (int m = 0; m < 4; ++m) {
            const int4 raw = *reinterpret_cast<const int4*>(XtsB + abyte + m * 8448 + kc * 2);
            af[m].i[0] = raw.x; af[m].i[1] = raw.y;
            af[m].i[2] = raw.z; af[m].i[3] = raw.w;
        }
        FragAB bf[4];
        #pragma unroll
        for (int n = 0; n < 4; ++n) {
            const char* p = WB + bB + kc * 2 - 32 * n;
            bf[n].l[0] = *reinterpret_cast<const unsigned long long*>(p);
            bf[n].l[1] = *reinterpret_cast<const unsigned long long*>(p + 8);
        }
        #pragma unroll
        for (int m = 0; m < 4; ++m)
            #pragma unroll
            for (int n = 0; n < 4; ++n)
                acc[m][n] = __builtin_amdgcn_mfma_f32_16x16x32_bf16(
                    af[m].v, bf[n].v, acc[m][n], 0, 0, 0);
    }

    // ---- epilogue: scale rows, nontemporal float4 stores; m outer / n inner
    // so each m emits a 4 KB-contiguous run over n ----
    #pragma unroll
    for (int m = 0; m < 4; ++m) {
        const int b_ = nt * 4 + m;
        float* obase = out + (((size_t)(b_ * 4 + h) * 8 + sx) * 8 + sy) * 4096
                       + laneG * 4;
        #pragma unroll
        for (int n = 0; n < 4; ++n) {
            const int j = wj0 + 16 * n + laneM;
            const float rt = rtab[j];
            f32x4 v = acc[m][n] * rt;
            __builtin_nontemporal_store(
                v, reinterpret_cast<f32x4*>(obase + (size_t)j * 16));
        }
    }
}

extern "C" void kernel_launch(void* const* d_in, const int* in_sizes, int n_in,
                              void* d_out, int out_size, void* d_ws, size_t ws_size,
                              hipStream_t stream) {
    const float* x    = (const float*)d_in[0];   // [16,8,256,16]
    const float* kern = (const float*)d_in[1];   // [4,8,8,256]
    float* out = (float*)d_out;                  // [16,4,8,8,256,16]

    k_fused<<<1024, 256, 0, stream>>>(x, kern, out);
}